// Round 3
// baseline (15.583 us; speedup 1.0000x reference)
//
#include <hip/hip_runtime.h>
#include <cstddef>

// Problem constants (fixed by reference setup_inputs):
//   out_seg: (8,6,11,192,192,1) f32  -> logits (N=48, K=11, P=36864) contiguous
//   segmentations: (8,6,192,192) int -> tgt (N, P)
//   label: (8,6) int                 -> mask (N)
constexpr int BLOCK = 256;
constexpr int ITEMS = 8;                        // pixels per thread
constexpr int KCLS  = 11;
constexpr int PPIX  = 192 * 192;                // 36864
constexpr int NROW  = 48;                       // B*S
constexpr int GRIDX = PPIX / (BLOCK * ITEMS);   // 18 (exact)

__device__ __forceinline__ float waveReduceSum(float v) {
#pragma unroll
    for (int off = 32; off > 0; off >>= 1)
        v += __shfl_down(v, off, 64);
    return v;
}

__global__ __launch_bounds__(BLOCK)
void focal_partial(const float* __restrict__ logits,
                   const int*   __restrict__ seg,
                   const int*   __restrict__ label,
                   float*       __restrict__ partial) {
    const int n   = blockIdx.y;
    const int bid = blockIdx.y * gridDim.x + blockIdx.x;
    __shared__ float smem[BLOCK / 64];

    float acc = 0.0f;
    if (label[n] != 0) {                        // block-uniform branch: whole row masked
        const int pbase = blockIdx.x * (BLOCK * ITEMS) + threadIdx.x;
        const int*   __restrict__ segn = seg    + n * PPIX;
        const float* __restrict__ logn = logits + (size_t)n * KCLS * PPIX;
#pragma unroll
        for (int it = 0; it < ITEMS; ++it) {
            const int   p     = pbase + it * BLOCK;   // coalesced seg read
            const int   t     = segn[p];
            const float logpt = logn[t * PPIX + p];   // gather: 1 of 11 class planes
            const float pt    = expf(logpt);
            const float u  = 1.0f - pt;               // can be large-negative; even power ok
            const float u2 = u * u;
            const float u6 = u2 * u2 * u2;            // (1-pt)^6, exact vs pow(.,6.0)
            acc = fmaf(-u6, logpt, acc);              // -(1-pt)^6 * logpt
        }
    }
    // deterministic block reduction
    acc = waveReduceSum(acc);
    const int lane = threadIdx.x & 63;
    const int wid  = threadIdx.x >> 6;
    if (lane == 0) smem[wid] = acc;
    __syncthreads();
    if (threadIdx.x == 0) {
        float s = smem[0];
#pragma unroll
        for (int w = 1; w < BLOCK / 64; ++w) s += smem[w];
        partial[bid] = s;                       // always written (ws is poisoned 0xAA)
    }
}

__global__ __launch_bounds__(256)
void focal_final(const float* __restrict__ partial, int nPartial,
                 const int*   __restrict__ label,   int nLabel,
                 float*       __restrict__ out) {
    __shared__ float ssum[4];
    __shared__ float scnt[4];

    float s = 0.0f;
    for (int i = threadIdx.x; i < nPartial; i += 256) s += partial[i];
    float c = 0.0f;
    for (int i = threadIdx.x; i < nLabel; i += 256) c += (label[i] != 0) ? 1.0f : 0.0f;

    s = waveReduceSum(s);
    c = waveReduceSum(c);
    const int lane = threadIdx.x & 63;
    const int wid  = threadIdx.x >> 6;
    if (lane == 0) { ssum[wid] = s; scnt[wid] = c; }
    __syncthreads();
    if (threadIdx.x == 0) {
        const float total = ssum[0] + ssum[1] + ssum[2] + ssum[3];
        const float cnt   = scnt[0] + scnt[1] + scnt[2] + scnt[3];
        const float loss  = total / cnt;
        out[0] = loss;   // loss (shape (1,))
        out[1] = 0.0f;   // recon = jnp.asarray(0)
        out[2] = loss;   // loss again (3rd tuple element)
    }
}

extern "C" void kernel_launch(void* const* d_in, const int* in_sizes, int n_in,
                              void* d_out, int out_size, void* d_ws, size_t ws_size,
                              hipStream_t stream) {
    const float* logits = (const float*)d_in[0];  // out_seg
    const int*   seg    = (const int*)d_in[1];    // segmentations
    const int*   label  = (const int*)d_in[2];    // label
    float* out     = (float*)d_out;
    float* partial = (float*)d_ws;                // 864 floats = 3.4 KB scratch

    dim3 grid(GRIDX, NROW);
    focal_partial<<<grid, BLOCK, 0, stream>>>(logits, seg, label, partial);
    focal_final<<<1, 256, 0, stream>>>(partial, GRIDX * NROW, label, NROW, out);
}